// Round 6
// baseline (307.442 us; speedup 1.0000x reference)
//
#include <hip/hip_runtime.h>
#include <hip/hip_bf16.h>

#define NN 100000
#define EE 1600000
#define NBC 98           // coarse buckets of 1024 nodes
#define CAPC 17408       // per-coarse capacity; mean 16327, +8 sigma
#define CHA 2048         // edges per binA block
#define NBLA 782         // ceil(EE/CHA)
#define NLIN ((NN + 63) / 64)
#define NTILE 3125       // 32 nodes per tile
#define NAGG (NTILE * 8) // 8 slots (4 feature slices x 2 halves) per tile

// workspace byte offsets (256-aligned)
#define OFF_CCNT 0u               // NBC*4 = 392
#define OFF_DEG  512u             // NN*4 = 400000
#define OFF_NS   400640u          // NN*4
#define OFF_CBUF 800768u          // NBC*CAPC*4 = 6823936
#define OFF_CSR  7624704u         // NBC*CAPC*4
#define OFF_P    14448640u        // NN*64*2 (bf16)
#define OFF_Q    27248640u        // NN*64*2
// total 40048640 B ~= 38.2 MB ; U lives in d_out (fp32)

__device__ __forceinline__ ushort f2bf(float f) {
  unsigned u = __float_as_uint(f);
  unsigned r = (u + 0x7FFFu + ((u >> 16) & 1u)) >> 16;
  return (ushort)r;
}
__device__ __forceinline__ float bf2f(ushort h) {
  return __uint_as_float(((unsigned)h) << 16);
}
__device__ __forceinline__ unsigned pk2(float a, float b) {
  return (unsigned)f2bf(a) | ((unsigned)f2bf(b) << 16);
}
__device__ __forceinline__ float uplo(unsigned u) {
  return __uint_as_float(u << 16);
}
__device__ __forceinline__ float uphi(unsigned u) {
  return __uint_as_float(u & 0xFFFF0000u);
}

// -------- binA: LDS counting-sort 2048-edge chunks into 98 coarse buckets ----
// entry: src(17b) | (d & 1023) << 17
__launch_bounds__(256)
__global__ void k_binA(const int* __restrict__ ei, int* __restrict__ ccnt,
                       unsigned* __restrict__ cbuf) {
  __shared__ int hist[NBC], offs[NBC], starts[NBC], gbase[NBC];
  __shared__ int wtot[4];
  __shared__ unsigned sorted[CHA];
  __shared__ ushort bkt[CHA];
  int t = threadIdx.x;
  if (t < NBC) hist[t] = 0;
  __syncthreads();
  unsigned ent[8];
  int cb[8];
  int e0 = blockIdx.x * CHA;
  #pragma unroll
  for (int it = 0; it < 8; ++it) {
    int e = e0 + t + it * 256;
    cb[it] = -1;
    if (e < EE) {
      int s = ei[e], d = ei[EE + e];
      ent[it] = (unsigned)s | ((unsigned)(d & 1023) << 17);
      cb[it] = d >> 10;
      atomicAdd(&hist[cb[it]], 1);
    }
  }
  __syncthreads();
  {  // exclusive scan of hist[0..NBC)
    int v = (t < NBC) ? hist[t] : 0;
    int x = v;
    #pragma unroll
    for (int off = 1; off < 64; off <<= 1) {
      int w = __shfl_up(x, off);
      if ((t & 63) >= off) x += w;
    }
    if ((t & 63) == 63) wtot[t >> 6] = x;
    __syncthreads();
    int pre = 0;
    #pragma unroll
    for (int w = 0; w < 4; ++w)
      if (w < (t >> 6)) pre += wtot[w];
    if (t < NBC) { offs[t] = pre + x - v; starts[t] = pre + x - v; }
  }
  __syncthreads();
  #pragma unroll
  for (int it = 0; it < 8; ++it) {
    if (cb[it] >= 0) {
      int pos = atomicAdd(&offs[cb[it]], 1);
      sorted[pos] = ent[it];
      bkt[pos] = (ushort)cb[it];
    }
  }
  __syncthreads();
  if (t < NBC) {
    int c = hist[t];
    gbase[t] = (c > 0) ? atomicAdd(&ccnt[t], c) : 0;
  }
  __syncthreads();
  int tot = min(EE - e0, CHA);
  for (int i = t; i < tot; i += 256) {
    int b = bkt[i];
    int dst = gbase[b] + (i - starts[b]);
    if (dst < CAPC) cbuf[b * CAPC + dst] = sorted[i];
  }
}

// -------- csr: per coarse bucket, 1024-way counting sort -> node-sorted CSR --
__launch_bounds__(1024)
__global__ void k_csr(const int* __restrict__ ccnt, const unsigned* __restrict__ cbuf,
                      unsigned* __restrict__ csr, int* __restrict__ ns,
                      int* __restrict__ deg) {
  __shared__ int hist[1024], offs[1024], starts[1024], wpre[16];
  int cb = blockIdx.x;
  int t = threadIdx.x;
  hist[t] = 0;
  __syncthreads();
  int tot = min(ccnt[cb], CAPC);
  const unsigned* cb_base = cbuf + cb * CAPC;
  for (int i = t; i < tot; i += 1024)
    atomicAdd(&hist[cb_base[i] >> 17], 1);
  __syncthreads();
  {  // block-wide exclusive scan of hist[1024]
    int v = hist[t];
    int x = v;
    int lane = t & 63;
    int w = t >> 6;
    #pragma unroll
    for (int off = 1; off < 64; off <<= 1) {
      int q = __shfl_up(x, off);
      if (lane >= off) x += q;
    }
    if (lane == 63) wpre[w] = x;
    __syncthreads();
    if (t < 16) {
      int s = wpre[t];
      int xx = s;
      #pragma unroll
      for (int off = 1; off < 16; off <<= 1) {
        int q = __shfl_up(xx, off);
        if (t >= off) xx += q;
      }
      wpre[t] = xx - s;  // exclusive wave prefix
    }
    __syncthreads();
    int ex = wpre[w] + x - v;
    offs[t] = ex;
    starts[t] = ex;
  }
  __syncthreads();
  for (int i = t; i < tot; i += 1024) {
    unsigned e = cb_base[i];
    int pos = atomicAdd(&offs[e >> 17], 1);
    csr[cb * CAPC + pos] = e & 0x1FFFFu;  // scatter local to 68KB window: L2-absorbed
  }
  int n = cb * 1024 + t;
  if (n < NN) {
    ns[n] = cb * CAPC + starts[t];
    deg[n] = hist[t];
  }
}

// ---------------- lin1: P = x@w1[:64], Qb = x@w1[64:] + b1 (bf16 out) ---------
__launch_bounds__(256)
__global__ void k_lin1(const float* __restrict__ x, const float* __restrict__ w1,
                       const float* __restrict__ b1, ushort* __restrict__ P,
                       ushort* __restrict__ Qb) {
  __shared__ float w1s[128 * 64];
  __shared__ float xs[64 * 66];
  int t = threadIdx.x;
  int base = blockIdx.x * 64;
  #pragma unroll
  for (int i = 0; i < 8; ++i) {
    int idx4 = t + i * 256;
    reinterpret_cast<float4*>(w1s)[idx4] = reinterpret_cast<const float4*>(w1)[idx4];
  }
  #pragma unroll
  for (int i = 0; i < 4; ++i) {
    int idx4 = t + i * 256;
    int r = idx4 >> 4, c = idx4 & 15;
    int grow = base + r;
    float4 v = make_float4(0.f, 0.f, 0.f, 0.f);
    if (grow < NN) v = reinterpret_cast<const float4*>(x)[grow * 16 + c];
    float* p = &xs[r * 66 + c * 4];
    *reinterpret_cast<float2*>(p) = make_float2(v.x, v.y);
    *reinterpret_cast<float2*>(p + 2) = make_float2(v.z, v.w);
  }
  __syncthreads();
  int tr = t >> 4, tc = t & 15;
  int half = tc >> 3;
  int c0 = (tc & 7) * 8;
  float acc[4][8];
  #pragma unroll
  for (int i = 0; i < 4; ++i)
    #pragma unroll
    for (int j = 0; j < 8; ++j) acc[i][j] = 0.f;
  #pragma unroll 4
  for (int k = 0; k < 64; ++k) {
    float a0 = xs[(4 * tr + 0) * 66 + k];
    float a1 = xs[(4 * tr + 1) * 66 + k];
    float a2 = xs[(4 * tr + 2) * 66 + k];
    float a3 = xs[(4 * tr + 3) * 66 + k];
    const float* bp = &w1s[(half * 64 + k) * 64 + c0];
    float4 w0 = *reinterpret_cast<const float4*>(bp);
    float4 w1v = *reinterpret_cast<const float4*>(bp + 4);
    float wf[8] = {w0.x, w0.y, w0.z, w0.w, w1v.x, w1v.y, w1v.z, w1v.w};
    #pragma unroll
    for (int j = 0; j < 8; ++j) {
      acc[0][j] = fmaf(a0, wf[j], acc[0][j]);
      acc[1][j] = fmaf(a1, wf[j], acc[1][j]);
      acc[2][j] = fmaf(a2, wf[j], acc[2][j]);
      acc[3][j] = fmaf(a3, wf[j], acc[3][j]);
    }
  }
  if (half) {
    #pragma unroll
    for (int j = 0; j < 8; ++j) {
      float bv = b1[c0 + j];
      #pragma unroll
      for (int i = 0; i < 4; ++i) acc[i][j] += bv;
    }
  }
  ushort* dstb = (half ? Qb : P);
  #pragma unroll
  for (int i = 0; i < 4; ++i) {
    int row = base + 4 * tr + i;
    if (row < NN) {
      uint4 o = make_uint4(pk2(acc[i][0], acc[i][1]), pk2(acc[i][2], acc[i][3]),
                           pk2(acc[i][4], acc[i][5]), pk2(acc[i][6], acc[i][7]));
      *reinterpret_cast<uint4*>(&dstb[row * 64 + c0]) = o;
    }
  }
}

// -------- agg: CSR gather, feature-sliced for per-XCD L2 residency ----------
// blockIdx = tile*8 + slot ; slot%8 ~ XCD ; slice f = slot>>1 (16 feats),
// half h = slot&1. Each XCD touches only a 3.2MB P-slice -> L2-resident.
// U (fp32) written into d_out.
__launch_bounds__(256)
__global__ void k_agg(const unsigned* __restrict__ csr, const int* __restrict__ ns,
                      const int* __restrict__ deg, const unsigned* __restrict__ Pu,
                      const unsigned* __restrict__ Qu, float* __restrict__ U) {
  int t = threadIdx.x;
  int slot = blockIdx.x & 7;
  int tile = blockIdx.x >> 3;
  int f = slot >> 1;
  int h = slot & 1;
  int w = t >> 6;
  int lane = t & 63;
  int eg = lane >> 3;      // 0..7 edge group
  int cu = lane & 7;       // 0..7 uint (2 feats) within slice
  int fo = f * 8 + cu;     // uint offset within 32-uint row
  #pragma unroll
  for (int g = 0; g < 4; ++g) {
    int n = tile * 32 + h * 16 + w * 4 + g;
    if (n >= NN) continue;
    int dg = deg[n];
    int st = ns[n];
    unsigned q = Qu[n * 32 + fo];
    float q0 = uplo(q), q1 = uphi(q);
    float a0 = 0.f, a1 = 0.f;
    int e = 0;
    while (e + 16 <= dg) {
      unsigned s0 = csr[st + e + eg];
      unsigned s1 = csr[st + e + 8 + eg];
      unsigned p0 = Pu[s0 * 32 + fo];
      unsigned p1 = Pu[s1 * 32 + fo];
      a0 += fmaxf(uplo(p0) + q0, 0.f); a1 += fmaxf(uphi(p0) + q1, 0.f);
      a0 += fmaxf(uplo(p1) + q0, 0.f); a1 += fmaxf(uphi(p1) + q1, 0.f);
      e += 16;
    }
    if (e + 8 <= dg) {
      unsigned s0 = csr[st + e + eg];
      unsigned p0 = Pu[s0 * 32 + fo];
      a0 += fmaxf(uplo(p0) + q0, 0.f); a1 += fmaxf(uphi(p0) + q1, 0.f);
      e += 8;
    }
    if (e + eg < dg) {
      unsigned s0 = csr[st + e + eg];
      unsigned p0 = Pu[s0 * 32 + fo];
      a0 += fmaxf(uplo(p0) + q0, 0.f); a1 += fmaxf(uphi(p0) + q1, 0.f);
    }
    a0 += __shfl_xor(a0, 8);  a1 += __shfl_xor(a1, 8);
    a0 += __shfl_xor(a0, 16); a1 += __shfl_xor(a1, 16);
    a0 += __shfl_xor(a0, 32); a1 += __shfl_xor(a1, 32);
    if (eg == 0) {
      float inv = 1.f / (float)max(dg, 1);
      *reinterpret_cast<float2*>(&U[n * 64 + f * 16 + cu * 2]) =
          make_float2(a0 * inv, a1 * inv);
    }
  }
}

// ---------------- final: out = u@w2 + x@ws + bs (+ b2 iff deg>0) -------------
// U aliases out (fp32, same layout); block stages its own tile before writing.
__launch_bounds__(256)
__global__ void k_final(const float* __restrict__ x, const float* __restrict__ U,
                        const float* __restrict__ w2, const float* __restrict__ b2,
                        const float* __restrict__ wsw, const float* __restrict__ bs,
                        const int* __restrict__ deg, float* __restrict__ out) {
  __shared__ float Wss[128 * 64];
  __shared__ float ts[64 * 66];
  int t = threadIdx.x;
  int base = blockIdx.x * 64;
  #pragma unroll
  for (int i = 0; i < 4; ++i) {
    int idx4 = t + i * 256;
    reinterpret_cast<float4*>(Wss)[idx4] = reinterpret_cast<const float4*>(w2)[idx4];
    reinterpret_cast<float4*>(Wss)[idx4 + 1024] = reinterpret_cast<const float4*>(wsw)[idx4];
  }
  #pragma unroll
  for (int i = 0; i < 4; ++i) {
    int idx4 = t + i * 256;
    int r = idx4 >> 4, c = idx4 & 15;
    int grow = base + r;
    float4 v = make_float4(0.f, 0.f, 0.f, 0.f);
    if (grow < NN) v = reinterpret_cast<const float4*>(U)[grow * 16 + c];
    float* p = &ts[r * 66 + c * 4];
    *reinterpret_cast<float2*>(p) = make_float2(v.x, v.y);
    *reinterpret_cast<float2*>(p + 2) = make_float2(v.z, v.w);
  }
  __syncthreads();
  int tr = t >> 4, tc = t & 15;
  float acc[4][4];
  #pragma unroll
  for (int i = 0; i < 4; ++i)
    #pragma unroll
    for (int j = 0; j < 4; ++j) acc[i][j] = 0.f;
  #pragma unroll 4
  for (int k = 0; k < 64; ++k) {
    float a0 = ts[(4 * tr + 0) * 66 + k];
    float a1 = ts[(4 * tr + 1) * 66 + k];
    float a2 = ts[(4 * tr + 2) * 66 + k];
    float a3 = ts[(4 * tr + 3) * 66 + k];
    float4 wv = *reinterpret_cast<const float4*>(&Wss[k * 64 + 4 * tc]);
    acc[0][0] = fmaf(a0, wv.x, acc[0][0]); acc[0][1] = fmaf(a0, wv.y, acc[0][1]);
    acc[0][2] = fmaf(a0, wv.z, acc[0][2]); acc[0][3] = fmaf(a0, wv.w, acc[0][3]);
    acc[1][0] = fmaf(a1, wv.x, acc[1][0]); acc[1][1] = fmaf(a1, wv.y, acc[1][1]);
    acc[1][2] = fmaf(a1, wv.z, acc[1][2]); acc[1][3] = fmaf(a1, wv.w, acc[1][3]);
    acc[2][0] = fmaf(a2, wv.x, acc[2][0]); acc[2][1] = fmaf(a2, wv.y, acc[2][1]);
    acc[2][2] = fmaf(a2, wv.z, acc[2][2]); acc[2][3] = fmaf(a2, wv.w, acc[2][3]);
    acc[3][0] = fmaf(a3, wv.x, acc[3][0]); acc[3][1] = fmaf(a3, wv.y, acc[3][1]);
    acc[3][2] = fmaf(a3, wv.z, acc[3][2]); acc[3][3] = fmaf(a3, wv.w, acc[3][3]);
  }
  __syncthreads();
  #pragma unroll
  for (int i = 0; i < 4; ++i) {
    int idx4 = t + i * 256;
    int r = idx4 >> 4, cc = idx4 & 15;
    int grow = base + r;
    float4 v = make_float4(0.f, 0.f, 0.f, 0.f);
    if (grow < NN) v = reinterpret_cast<const float4*>(x)[grow * 16 + cc];
    float* p = &ts[r * 66 + cc * 4];
    *reinterpret_cast<float2*>(p) = make_float2(v.x, v.y);
    *reinterpret_cast<float2*>(p + 2) = make_float2(v.z, v.w);
  }
  __syncthreads();
  #pragma unroll 4
  for (int k = 0; k < 64; ++k) {
    float a0 = ts[(4 * tr + 0) * 66 + k];
    float a1 = ts[(4 * tr + 1) * 66 + k];
    float a2 = ts[(4 * tr + 2) * 66 + k];
    float a3 = ts[(4 * tr + 3) * 66 + k];
    float4 wv = *reinterpret_cast<const float4*>(&Wss[(64 + k) * 64 + 4 * tc]);
    acc[0][0] = fmaf(a0, wv.x, acc[0][0]); acc[0][1] = fmaf(a0, wv.y, acc[0][1]);
    acc[0][2] = fmaf(a0, wv.z, acc[0][2]); acc[0][3] = fmaf(a0, wv.w, acc[0][3]);
    acc[1][0] = fmaf(a1, wv.x, acc[1][0]); acc[1][1] = fmaf(a1, wv.y, acc[1][1]);
    acc[1][2] = fmaf(a1, wv.z, acc[1][2]); acc[1][3] = fmaf(a1, wv.w, acc[1][3]);
    acc[2][0] = fmaf(a2, wv.x, acc[2][0]); acc[2][1] = fmaf(a2, wv.y, acc[2][1]);
    acc[2][2] = fmaf(a2, wv.z, acc[2][2]); acc[2][3] = fmaf(a2, wv.w, acc[2][3]);
    acc[3][0] = fmaf(a3, wv.x, acc[3][0]); acc[3][1] = fmaf(a3, wv.y, acc[3][1]);
    acc[3][2] = fmaf(a3, wv.z, acc[3][2]); acc[3][3] = fmaf(a3, wv.w, acc[3][3]);
  }
  #pragma unroll
  for (int i = 0; i < 4; ++i) {
    int rl = 4 * tr + i;
    int row = base + rl;
    if (row < NN) {
      float bsc = (deg[row] > 0) ? 1.f : 0.f;
      float4 o;
      o.x = acc[i][0] + bs[4 * tc + 0] + bsc * b2[4 * tc + 0];
      o.y = acc[i][1] + bs[4 * tc + 1] + bsc * b2[4 * tc + 1];
      o.z = acc[i][2] + bs[4 * tc + 2] + bsc * b2[4 * tc + 2];
      o.w = acc[i][3] + bs[4 * tc + 3] + bsc * b2[4 * tc + 3];
      *reinterpret_cast<float4*>(&out[row * 64 + 4 * tc]) = o;
    }
  }
}

extern "C" void kernel_launch(void* const* d_in, const int* in_sizes, int n_in,
                              void* d_out, int out_size, void* d_ws, size_t ws_size,
                              hipStream_t stream) {
  const float* x   = (const float*)d_in[0];
  const int*   ei  = (const int*)d_in[1];
  const float* w1  = (const float*)d_in[2];
  const float* b1  = (const float*)d_in[3];
  const float* w2  = (const float*)d_in[4];
  const float* b2  = (const float*)d_in[5];
  const float* wsw = (const float*)d_in[6];
  const float* bs  = (const float*)d_in[7];
  float* out = (float*)d_out;
  char* ws = (char*)d_ws;
  int* ccnt      = (int*)(ws + OFF_CCNT);
  int* deg       = (int*)(ws + OFF_DEG);
  int* ns        = (int*)(ws + OFF_NS);
  unsigned* cbuf = (unsigned*)(ws + OFF_CBUF);
  unsigned* csr  = (unsigned*)(ws + OFF_CSR);
  ushort* P      = (ushort*)(ws + OFF_P);
  ushort* Qb     = (ushort*)(ws + OFF_Q);

  hipMemsetAsync(ccnt, 0, NBC * sizeof(int), stream);
  k_binA<<<NBLA, 256, 0, stream>>>(ei, ccnt, cbuf);
  k_lin1<<<NLIN, 256, 0, stream>>>(x, w1, b1, P, Qb);
  k_csr<<<NBC, 1024, 0, stream>>>(ccnt, cbuf, csr, ns, deg);
  k_agg<<<NAGG, 256, 0, stream>>>(csr, ns, deg, (const unsigned*)P,
                                  (const unsigned*)Qb, out);
  k_final<<<NLIN, 256, 0, stream>>>(x, out, w2, b2, wsw, bs, deg, out);
}

// Round 8
// 233.376 us; speedup vs baseline: 1.3174x; 1.3174x over previous
//
#include <hip/hip_runtime.h>
#include <hip/hip_bf16.h>

#define NN 100000
#define EE 1600000
#define NBC 98           // coarse buckets of 1024 nodes
#define CAPC 17408       // per-coarse capacity; mean 16327, +8 sigma
#define CHA 2048         // edges per binA block
#define NBLA 782         // ceil(EE/CHA)
#define NLIN ((NN + 63) / 64)

// workspace byte offsets (256-aligned)
#define OFF_CCNT 0u               // NBC*4 = 392
#define OFF_DEG  512u             // NN*4
#define OFF_NS   400640u          // NN*4
#define OFF_CBUF 800768u          // NBC*CAPC*4 = 6823936
#define OFF_CSR  7624704u         // NBC*CAPC*4
#define OFF_P    14448640u        // NN*64*2 (bf16)
#define OFF_Q    27248640u        // NN*64*2
#define OFF_W1T  40048640u        // 128*64*2 (bf16, [c_ext][k] transposed w1)
#define OFF_WFT  40065024u        // 64*128*2 (bf16, [col][k] of [w2;ws])
// total 40081408 B ~= 38.2 MB ; U (fp32) lives in d_out

typedef __attribute__((ext_vector_type(8))) short bf16x8;
typedef __attribute__((ext_vector_type(4))) float f32x4;

__device__ __forceinline__ ushort f2bf(float f) {
  unsigned u = __float_as_uint(f);
  unsigned r = (u + 0x7FFFu + ((u >> 16) & 1u)) >> 16;
  return (ushort)r;
}
__device__ __forceinline__ unsigned pk2(float a, float b) {
  return (unsigned)f2bf(a) | ((unsigned)f2bf(b) << 16);
}
__device__ __forceinline__ float uplo(unsigned u) {
  return __uint_as_float(u << 16);
}
__device__ __forceinline__ float uphi(unsigned u) {
  return __uint_as_float(u & 0xFFFF0000u);
}

// -------- binA: LDS counting-sort 2048-edge chunks into 98 coarse buckets ----
// blockIdx == NBLA additionally builds w1T / WfT (bf16 transposed weights).
__launch_bounds__(256)
__global__ void k_binA(const int* __restrict__ ei, int* __restrict__ ccnt,
                       unsigned* __restrict__ cbuf,
                       const float* __restrict__ w1, const float* __restrict__ w2,
                       const float* __restrict__ wsw,
                       ushort* __restrict__ w1T, ushort* __restrict__ WfT) {
  __shared__ int hist[NBC], offs[NBC], starts[NBC], gbase[NBC];
  __shared__ int wtot[4];
  __shared__ unsigned sorted[CHA];
  __shared__ ushort bkt[CHA];
  int t = threadIdx.x;
  if (blockIdx.x == NBLA) {
    // w1T[c_ext*64 + k] = w1[(half*64 + k)*64 + col], col=c_ext&63, half=c_ext>>6
    for (int idx = t; idx < 8192; idx += 256) {
      int ce = idx >> 6, k = idx & 63;
      int col = ce & 63, half = ce >> 6;
      w1T[idx] = f2bf(w1[(half * 64 + k) * 64 + col]);
    }
    // WfT[col*128 + k] = k<64 ? w2[k][col] : ws[k-64][col]
    for (int idx = t; idx < 8192; idx += 256) {
      int c = idx >> 7, k = idx & 127;
      WfT[idx] = f2bf(k < 64 ? w2[k * 64 + c] : wsw[(k - 64) * 64 + c]);
    }
    return;
  }
  if (t < NBC) hist[t] = 0;
  __syncthreads();
  unsigned ent[8];
  int cb[8];
  int e0 = blockIdx.x * CHA;
  #pragma unroll
  for (int it = 0; it < 8; ++it) {
    int e = e0 + t + it * 256;
    cb[it] = -1;
    if (e < EE) {
      int s = ei[e], d = ei[EE + e];
      ent[it] = (unsigned)s | ((unsigned)(d & 1023) << 17);
      cb[it] = d >> 10;
      atomicAdd(&hist[cb[it]], 1);
    }
  }
  __syncthreads();
  {  // exclusive scan of hist[0..NBC)
    int v = (t < NBC) ? hist[t] : 0;
    int x = v;
    #pragma unroll
    for (int off = 1; off < 64; off <<= 1) {
      int w = __shfl_up(x, off);
      if ((t & 63) >= off) x += w;
    }
    if ((t & 63) == 63) wtot[t >> 6] = x;
    __syncthreads();
    int pre = 0;
    #pragma unroll
    for (int w = 0; w < 4; ++w)
      if (w < (t >> 6)) pre += wtot[w];
    if (t < NBC) { offs[t] = pre + x - v; starts[t] = pre + x - v; }
  }
  __syncthreads();
  #pragma unroll
  for (int it = 0; it < 8; ++it) {
    if (cb[it] >= 0) {
      int pos = atomicAdd(&offs[cb[it]], 1);
      sorted[pos] = ent[it];
      bkt[pos] = (ushort)cb[it];
    }
  }
  __syncthreads();
  if (t < NBC) {
    int c = hist[t];
    gbase[t] = (c > 0) ? atomicAdd(&ccnt[t], c) : 0;
  }
  __syncthreads();
  int tot = min(EE - e0, CHA);
  for (int i = t; i < tot; i += 256) {
    int b = bkt[i];
    int dst = gbase[b] + (i - starts[b]);
    if (dst < CAPC) cbuf[b * CAPC + dst] = sorted[i];
  }
}

// -------- csr: per coarse bucket, 1024-way counting sort -> node-sorted CSR --
__launch_bounds__(1024)
__global__ void k_csr(const int* __restrict__ ccnt, const unsigned* __restrict__ cbuf,
                      unsigned* __restrict__ csr, int* __restrict__ ns,
                      int* __restrict__ deg) {
  __shared__ int hist[1024], offs[1024], starts[1024], wpre[16];
  int cb = blockIdx.x;
  int t = threadIdx.x;
  hist[t] = 0;
  __syncthreads();
  int tot = min(ccnt[cb], CAPC);
  const unsigned* cb_base = cbuf + cb * CAPC;
  for (int i = t; i < tot; i += 1024)
    atomicAdd(&hist[cb_base[i] >> 17], 1);
  __syncthreads();
  {  // block-wide exclusive scan of hist[1024]
    int v = hist[t];
    int x = v;
    int lane = t & 63;
    int w = t >> 6;
    #pragma unroll
    for (int off = 1; off < 64; off <<= 1) {
      int q = __shfl_up(x, off);
      if (lane >= off) x += q;
    }
    if (lane == 63) wpre[w] = x;
    __syncthreads();
    if (t < 16) {
      int s = wpre[t];
      int xx = s;
      #pragma unroll
      for (int off = 1; off < 16; off <<= 1) {
        int q = __shfl_up(xx, off);
        if (t >= off) xx += q;
      }
      wpre[t] = xx - s;
    }
    __syncthreads();
    int ex = wpre[w] + x - v;
    offs[t] = ex;
    starts[t] = ex;
  }
  __syncthreads();
  for (int i = t; i < tot; i += 1024) {
    unsigned e = cb_base[i];
    int pos = atomicAdd(&offs[e >> 17], 1);
    csr[cb * CAPC + pos] = e & 0x1FFFFu;  // scatter within 68KB window: L2-absorbed
  }
  int n = cb * 1024 + t;
  if (n < NN) {
    ns[n] = cb * CAPC + starts[t];
    deg[n] = hist[t];
  }
}

// -------- lin1 (MFMA): P = x@w1[:64], Qb = x@w1[64:] + b1  (bf16 out) --------
__launch_bounds__(256)
__global__ void k_lin1(const float* __restrict__ x, const ushort* __restrict__ w1T,
                       const float* __restrict__ b1, ushort* __restrict__ P,
                       ushort* __restrict__ Qb) {
  __shared__ ushort xbf[64 * 72];  // bf16 x tile, pitch 72 (16B aligned rows)
  int t = threadIdx.x;
  int base = blockIdx.x * 64;
  #pragma unroll
  for (int i = 0; i < 4; ++i) {
    int idx4 = t + i * 256;
    int r = idx4 >> 4, c = idx4 & 15;
    int grow = base + r;
    float4 v = make_float4(0.f, 0.f, 0.f, 0.f);
    if (grow < NN) v = reinterpret_cast<const float4*>(x)[grow * 16 + c];
    *reinterpret_cast<uint2*>(&xbf[r * 72 + c * 4]) =
        make_uint2(pk2(v.x, v.y), pk2(v.z, v.w));
  }
  __syncthreads();
  int w = t >> 6, l = t & 63;
  int li = l & 15, lg = l >> 4;
  f32x4 acc[8];
  #pragma unroll
  for (int n = 0; n < 8; ++n) acc[n] = (f32x4){0.f, 0.f, 0.f, 0.f};
  #pragma unroll
  for (int s = 0; s < 2; ++s) {
    bf16x8 a = *reinterpret_cast<const bf16x8*>(&xbf[(w * 16 + li) * 72 + s * 32 + lg * 8]);
    #pragma unroll
    for (int n = 0; n < 8; ++n) {
      bf16x8 b = *reinterpret_cast<const bf16x8*>(&w1T[(n * 16 + li) * 64 + s * 32 + lg * 8]);
      acc[n] = __builtin_amdgcn_mfma_f32_16x16x32_bf16(a, b, acc[n], 0, 0, 0);
    }
  }
  #pragma unroll
  for (int n = 0; n < 8; ++n) {
    int col = (n & 3) * 16 + li;
    ushort* dstb = (n < 4) ? P : Qb;
    float badd = (n < 4) ? 0.f : b1[col];
    #pragma unroll
    for (int q = 0; q < 4; ++q) {
      int row = base + w * 16 + lg * 4 + q;
      if (row < NN) dstb[row * 64 + col] = f2bf(acc[n][q] + badd);
    }
  }
}

// -------- agg: CSR full-row gather; U (fp32) into d_out ----------------------
__launch_bounds__(256)
__global__ void k_agg(const unsigned* __restrict__ csr, const int* __restrict__ ns,
                      const int* __restrict__ deg, const uint2* __restrict__ P2,
                      const uint2* __restrict__ Q2, float* __restrict__ Uo) {
  int t = threadIdx.x;
  int w = t >> 6, lane = t & 63;
  int eg = lane >> 4, c = lane & 15;
  int nb = blockIdx.x * 64 + w * 16;
  for (int k = 0; k < 16; ++k) {
    int n = nb + k;
    if (n >= NN) return;
    int dg = deg[n], st = ns[n];
    uint2 q = Q2[n * 16 + c];
    float q0 = uplo(q.x), q1 = uphi(q.x), q2 = uplo(q.y), q3 = uphi(q.y);
    float a0 = 0.f, a1 = 0.f, a2 = 0.f, a3 = 0.f;
    int e = eg;
    while (e + 4 < dg) {
      unsigned s0 = csr[st + e];
      unsigned s1 = csr[st + e + 4];
      uint2 p0 = P2[s0 * 16 + c];
      uint2 p1 = P2[s1 * 16 + c];
      a0 += fmaxf(uplo(p0.x) + q0, 0.f); a1 += fmaxf(uphi(p0.x) + q1, 0.f);
      a2 += fmaxf(uplo(p0.y) + q2, 0.f); a3 += fmaxf(uphi(p0.y) + q3, 0.f);
      a0 += fmaxf(uplo(p1.x) + q0, 0.f); a1 += fmaxf(uphi(p1.x) + q1, 0.f);
      a2 += fmaxf(uplo(p1.y) + q2, 0.f); a3 += fmaxf(uphi(p1.y) + q3, 0.f);
      e += 8;
    }
    if (e < dg) {
      unsigned s0 = csr[st + e];
      uint2 p0 = P2[s0 * 16 + c];
      a0 += fmaxf(uplo(p0.x) + q0, 0.f); a1 += fmaxf(uphi(p0.x) + q1, 0.f);
      a2 += fmaxf(uplo(p0.y) + q2, 0.f); a3 += fmaxf(uphi(p0.y) + q3, 0.f);
    }
    a0 += __shfl_xor(a0, 16); a0 += __shfl_xor(a0, 32);
    a1 += __shfl_xor(a1, 16); a1 += __shfl_xor(a1, 32);
    a2 += __shfl_xor(a2, 16); a2 += __shfl_xor(a2, 32);
    a3 += __shfl_xor(a3, 16); a3 += __shfl_xor(a3, 32);
    if (eg == 0) {
      float inv = 1.f / (float)max(dg, 1);
      *reinterpret_cast<float4*>(&Uo[n * 64 + c * 4]) =
          make_float4(a0 * inv, a1 * inv, a2 * inv, a3 * inv);
    }
  }
}

// -------- final (MFMA): out = [u,x]@WfT^T + bs (+ b2 iff deg>0) --------------
// U (fp32) aliases out; each block stages its own tile before overwriting.
__launch_bounds__(256)
__global__ void k_final(const float* __restrict__ x, const float* __restrict__ U,
                        const ushort* __restrict__ WfT, const float* __restrict__ b2,
                        const float* __restrict__ bs, const int* __restrict__ deg,
                        float* __restrict__ out) {
  __shared__ ushort ubf[64 * 72];
  __shared__ ushort xbf[64 * 72];
  int t = threadIdx.x;
  int base = blockIdx.x * 64;
  #pragma unroll
  for (int i = 0; i < 4; ++i) {
    int idx4 = t + i * 256;
    int r = idx4 >> 4, c = idx4 & 15;
    int grow = base + r;
    float4 u = make_float4(0.f, 0.f, 0.f, 0.f);
    float4 v = make_float4(0.f, 0.f, 0.f, 0.f);
    if (grow < NN) {
      u = reinterpret_cast<const float4*>(U)[grow * 16 + c];
      v = reinterpret_cast<const float4*>(x)[grow * 16 + c];
    }
    *reinterpret_cast<uint2*>(&ubf[r * 72 + c * 4]) =
        make_uint2(pk2(u.x, u.y), pk2(u.z, u.w));
    *reinterpret_cast<uint2*>(&xbf[r * 72 + c * 4]) =
        make_uint2(pk2(v.x, v.y), pk2(v.z, v.w));
  }
  __syncthreads();
  int w = t >> 6, l = t & 63;
  int li = l & 15, lg = l >> 4;
  f32x4 acc[4];
  #pragma unroll
  for (int n = 0; n < 4; ++n) acc[n] = (f32x4){0.f, 0.f, 0.f, 0.f};
  #pragma unroll
  for (int s = 0; s < 4; ++s) {
    const ushort* src = (s < 2) ? ubf : xbf;
    bf16x8 a = *reinterpret_cast<const bf16x8*>(&src[(w * 16 + li) * 72 + (s & 1) * 32 + lg * 8]);
    #pragma unroll
    for (int n = 0; n < 4; ++n) {
      bf16x8 b = *reinterpret_cast<const bf16x8*>(&WfT[(n * 16 + li) * 128 + s * 32 + lg * 8]);
      acc[n] = __builtin_amdgcn_mfma_f32_16x16x32_bf16(a, b, acc[n], 0, 0, 0);
    }
  }
  #pragma unroll
  for (int n = 0; n < 4; ++n) {
    int col = n * 16 + li;
    float bsv = bs[col], b2v = b2[col];
    #pragma unroll
    for (int q = 0; q < 4; ++q) {
      int row = base + w * 16 + lg * 4 + q;
      if (row < NN) {
        float add = (deg[row] > 0) ? b2v : 0.f;
        out[row * 64 + col] = acc[n][q] + bsv + add;
      }
    }
  }
}

extern "C" void kernel_launch(void* const* d_in, const int* in_sizes, int n_in,
                              void* d_out, int out_size, void* d_ws, size_t ws_size,
                              hipStream_t stream) {
  const float* x   = (const float*)d_in[0];
  const int*   ei  = (const int*)d_in[1];
  const float* w1  = (const float*)d_in[2];
  const float* b1  = (const float*)d_in[3];
  const float* w2  = (const float*)d_in[4];
  const float* b2  = (const float*)d_in[5];
  const float* wsw = (const float*)d_in[6];
  const float* bs  = (const float*)d_in[7];
  float* out = (float*)d_out;
  char* ws = (char*)d_ws;
  int* ccnt      = (int*)(ws + OFF_CCNT);
  int* deg       = (int*)(ws + OFF_DEG);
  int* ns        = (int*)(ws + OFF_NS);
  unsigned* cbuf = (unsigned*)(ws + OFF_CBUF);
  unsigned* csr  = (unsigned*)(ws + OFF_CSR);
  ushort* P      = (ushort*)(ws + OFF_P);
  ushort* Qb     = (ushort*)(ws + OFF_Q);
  ushort* w1T    = (ushort*)(ws + OFF_W1T);
  ushort* WfT    = (ushort*)(ws + OFF_WFT);

  hipMemsetAsync(ccnt, 0, NBC * sizeof(int), stream);
  k_binA<<<NBLA + 1, 256, 0, stream>>>(ei, ccnt, cbuf, w1, w2, wsw, w1T, WfT);
  k_lin1<<<NLIN, 256, 0, stream>>>(x, w1T, b1, P, Qb);
  k_csr<<<NBC, 1024, 0, stream>>>(ccnt, cbuf, csr, ns, deg);
  k_agg<<<NLIN, 256, 0, stream>>>(csr, ns, deg, (const uint2*)P, (const uint2*)Qb, out);
  k_final<<<NLIN, 256, 0, stream>>>(x, out, WfT, b2, bs, deg, out);
}